// Round 5
// baseline (25.121 us; speedup 1.0000x reference)
//
#include <hip/hip_runtime.h>

#define KSIZE 5
#define HALF 2
#define IMG_W 512
#define IMG_H 512
#define HALF_W 256                 // px per wave (half a row)
#define CHUNK 8                    // output rows per wave
#define NLOADS (CHUNK + 2 * HALF)  // 12 input rows per wave
#define NTHREADS 256
#define NWAVES (NTHREADS / 64)

typedef float f32x2 __attribute__((ext_vector_type(2)));

__device__ __forceinline__ int reflect_idx(int i, int n) {
    // jnp.pad mode='reflect' (edge not repeated)
    if (i < 0) i = -i;
    if (i >= n) i = 2 * n - 2 - i;
    return i;
}

__global__ __launch_bounds__(NTHREADS)
void usm_kernel(const float* __restrict__ img,
                const float* __restrict__ params,
                float* __restrict__ out) {
    const int bc     = blockIdx.y;          // b*3 + c
    const int b      = bc / 3;
    const int half   = blockIdx.x & 1;      // 0: px 0..255, 1: px 256..511
    const int rowgrp = blockIdx.x >> 1;
    const int wave   = threadIdx.x >> 6;
    const int lane   = threadIdx.x & 63;
    const int r0     = (rowgrp * NWAVES + wave) * CHUNK;
    const int c0     = half * HALF_W;
    const int base   = c0 + 4 * lane;       // first px this lane owns

    // --- per-batch gaussian taps + sharpen amount
    float sigma  = 2.0f * params[b * 2 + 0];
    sigma        = fmaxf(sigma, 0.001f);
    const float amount = 2.0f * params[b * 2 + 1];

    float k[KSIZE];
    float ksum = 0.0f;
    const float inv2s2 = 1.0f / (2.0f * sigma * sigma);
#pragma unroll
    for (int i = 0; i < KSIZE; ++i) {
        const float x = (float)(i - HALF);
        k[i] = expf(-x * x * inv2s2);
        ksum += k[i];
    }
    const float kinv = 1.0f / ksum;
#pragma unroll
    for (int i = 0; i < KSIZE; ++i) k[i] *= kinv;

    const float* src = img + (size_t)bc * IMG_H * IMG_W;
    float*       dst = out + (size_t)bc * IMG_H * IMG_W;

    // clamped bases for the two 8B halo loads (uniform per lane, computed once)
    int lb = base - 2; lb = lb < 0   ? 0   : lb;
    int rb = base + 4; rb = rb > 510 ? 510 : rb;

    f32x2 h[KSIZE][2];   // ring of h-conv rows, packed px pairs (static-indexed)
    f32x2 o[3][2];       // ring of original rows, packed      (static-indexed)

#pragma unroll
    for (int s = 0; s < NLOADS; ++s) {
        // ---- load row slice: one aligned float4 + two overlapping 8B halo loads
        const int ri = reflect_idx(r0 + s - HALF, IMG_H);
        const float* row = src + (size_t)ri * IMG_W;
        const float4 a = *(const float4*)(row + base);     // px base..base+3
        const float2 L = *(const float2*)(row + lb);       // px base-2,base-1 (clamped)
        const float2 R = *(const float2*)(row + rb);       // px base+4,base+5 (clamped)

        // window x[0..7] = px base-2 .. base+5, with reflect at image edges
        const float x0 = (base == 0)   ? a.z : L.x;   // reflect: x[-2]=x[2]
        const float x1 = (base == 0)   ? a.y : L.y;   // reflect: x[-1]=x[1]
        const float x6 = (base == 508) ? a.z : R.x;   // reflect: x[512]=x[510]
        const float x7 = (base == 508) ? a.y : R.y;   // reflect: x[513]=x[509]

        // packed pairs: P* aligned, M* misaligned
        const f32x2 P0 = {x0, x1};
        const f32x2 P1 = {a.x, a.y};
        const f32x2 P2 = {a.z, a.w};
        const f32x2 P3 = {x6, x7};
        const f32x2 M0 = {x1, a.x};
        const f32x2 M1 = {a.y, a.z};
        const f32x2 M2 = {a.w, x6};

        // ---- horizontal conv (packed): t01 = conv at px base,base+1; t23 at +2,+3
        f32x2 t01 = k[0] * P0 + k[1] * M0 + k[2] * P1 + k[3] * M1 + k[4] * P2;
        f32x2 t23 = k[0] * P1 + k[1] * M1 + k[2] * P2 + k[3] * M2 + k[4] * P3;
        h[s % KSIZE][0] = t01;
        h[s % KSIZE][1] = t23;

        // ---- original row ring (packed)
        o[s % 3][0] = P1;
        o[s % 3][1] = P2;

        // ---- once 5 h-rows live, emit output row ro = r0 + s - 4
        if (s >= 2 * HALF) {
            const int ro = r0 + s - 2 * HALF;
            const int oc = (s - HALF) % 3;

            f32x2 b01 = {0.0f, 0.0f}, b23 = {0.0f, 0.0f};
#pragma unroll
            for (int j = 0; j < KSIZE; ++j) {
                b01 += k[j] * h[(s - 2 * HALF + j) % KSIZE][0];
                b23 += k[j] * h[(s - 2 * HALF + j) % KSIZE][1];
            }
            const f32x2 o01 = o[oc][0];
            const f32x2 o23 = o[oc][1];
            f32x2 v01 = o01 + amount * (o01 - b01);
            f32x2 v23 = o23 + amount * (o23 - b23);
            float4 v;
            v.x = fminf(fmaxf(v01.x, 0.0f), 1.0f);
            v.y = fminf(fmaxf(v01.y, 0.0f), 1.0f);
            v.z = fminf(fmaxf(v23.x, 0.0f), 1.0f);
            v.w = fminf(fmaxf(v23.y, 0.0f), 1.0f);
            *(float4*)(dst + (size_t)ro * IMG_W + base) = v;
        }
    }
}

extern "C" void kernel_launch(void* const* d_in, const int* in_sizes, int n_in,
                              void* d_out, int out_size, void* d_ws, size_t ws_size,
                              hipStream_t stream) {
    const float* img    = (const float*)d_in[0];
    const float* params = (const float*)d_in[1];
    float* out = (float*)d_out;

    // grid.x: 16 row-groups (4 waves x CHUNK=8 rows each) x 2 half-rows
    dim3 grid((IMG_H / (CHUNK * NWAVES)) * 2, 16 * 3);   // (32, 48)
    dim3 block(NTHREADS);
    usm_kernel<<<grid, block, 0, stream>>>(img, params, out);
}

// Round 7
// 24.433 us; speedup vs baseline: 1.0281x; 1.0281x over previous
//
#include <hip/hip_runtime.h>

#define KSIZE 5
#define HALF 2
#define IMG_W 512
#define IMG_H 512
#define HALF_W 256                 // px per wave (half a row)
#define CHUNK 4                    // output rows per wave
#define NLOADS (CHUNK + 2 * HALF)  // 8 input rows per wave
#define NTHREADS 256
#define NWAVES (NTHREADS / 64)

typedef float f32x2 __attribute__((ext_vector_type(2)));
typedef float f32x4 __attribute__((ext_vector_type(4)));

__device__ __forceinline__ int reflect_idx(int i, int n) {
    // jnp.pad mode='reflect' (edge not repeated)
    if (i < 0) i = -i;
    if (i >= n) i = 2 * n - 2 - i;
    return i;
}

__global__ __launch_bounds__(NTHREADS)
void usm_kernel(const float* __restrict__ img,
                const float* __restrict__ params,
                float* __restrict__ out) {
    const int bc     = blockIdx.y;          // b*3 + c
    const int b      = bc / 3;
    const int half   = blockIdx.x & 1;      // 0: px 0..255, 1: px 256..511
    const int rowgrp = blockIdx.x >> 1;
    const int wave   = threadIdx.x >> 6;
    const int lane   = threadIdx.x & 63;
    const int r0     = (rowgrp * NWAVES + wave) * CHUNK;
    const int c0     = half * HALF_W;
    const int base   = c0 + 4 * lane;       // first px this lane owns

    // --- per-batch gaussian taps + sharpen amount
    float sigma  = 2.0f * params[b * 2 + 0];
    sigma        = fmaxf(sigma, 0.001f);
    const float amount = 2.0f * params[b * 2 + 1];

    float k[KSIZE];
    float ksum = 0.0f;
    const float inv2s2 = 1.0f / (2.0f * sigma * sigma);
#pragma unroll
    for (int i = 0; i < KSIZE; ++i) {
        const float x = (float)(i - HALF);
        k[i] = expf(-x * x * inv2s2);
        ksum += k[i];
    }
    const float kinv = 1.0f / ksum;
#pragma unroll
    for (int i = 0; i < KSIZE; ++i) k[i] *= kinv;

    const float* src = img + (size_t)bc * IMG_H * IMG_W;
    float*       dst = out + (size_t)bc * IMG_H * IMG_W;

    // clamped bases for the two 8B halo loads (uniform per lane, computed once)
    int lb = base - 2; lb = lb < 0   ? 0   : lb;
    int rb = base + 4; rb = rb > 510 ? 510 : rb;

    f32x2 h[KSIZE][2];   // ring of h-conv rows, packed px pairs (static-indexed)
    f32x2 o[3][2];       // ring of original rows, packed      (static-indexed)

#pragma unroll
    for (int s = 0; s < NLOADS; ++s) {
        // ---- load row slice: one aligned 16B + two overlapping 8B halo loads
        const int ri = reflect_idx(r0 + s - HALF, IMG_H);
        const float* row = src + (size_t)ri * IMG_W;
        const f32x4 a = *(const f32x4*)(row + base);       // px base..base+3
        const f32x2 L = *(const f32x2*)(row + lb);         // px base-2,base-1 (clamped)
        const f32x2 R = *(const f32x2*)(row + rb);         // px base+4,base+5 (clamped)

        // window x[0..7] = px base-2 .. base+5, with reflect at image edges
        const float x0 = (base == 0)   ? a.z : L.x;   // reflect: x[-2]=x[2]
        const float x1 = (base == 0)   ? a.y : L.y;   // reflect: x[-1]=x[1]
        const float x6 = (base == 508) ? a.z : R.x;   // reflect: x[512]=x[510]
        const float x7 = (base == 508) ? a.y : R.y;   // reflect: x[513]=x[509]

        // packed pairs: P* aligned, M* misaligned
        const f32x2 P0 = {x0, x1};
        const f32x2 P1 = {a.x, a.y};
        const f32x2 P2 = {a.z, a.w};
        const f32x2 P3 = {x6, x7};
        const f32x2 M0 = {x1, a.x};
        const f32x2 M1 = {a.y, a.z};
        const f32x2 M2 = {a.w, x6};

        // ---- horizontal conv (packed): t01 = conv at px base,base+1; t23 at +2,+3
        f32x2 t01 = k[0] * P0 + k[1] * M0 + k[2] * P1 + k[3] * M1 + k[4] * P2;
        f32x2 t23 = k[0] * P1 + k[1] * M1 + k[2] * P2 + k[3] * M2 + k[4] * P3;
        h[s % KSIZE][0] = t01;
        h[s % KSIZE][1] = t23;

        // ---- original row ring (packed)
        o[s % 3][0] = P1;
        o[s % 3][1] = P2;

        // ---- once 5 h-rows live, emit output row ro = r0 + s - 4
        if (s >= 2 * HALF) {
            const int ro = r0 + s - 2 * HALF;
            const int oc = (s - HALF) % 3;

            f32x2 b01 = {0.0f, 0.0f}, b23 = {0.0f, 0.0f};
#pragma unroll
            for (int j = 0; j < KSIZE; ++j) {
                b01 += k[j] * h[(s - 2 * HALF + j) % KSIZE][0];
                b23 += k[j] * h[(s - 2 * HALF + j) % KSIZE][1];
            }
            const f32x2 o01 = o[oc][0];
            const f32x2 o23 = o[oc][1];
            f32x2 v01 = o01 + amount * (o01 - b01);
            f32x2 v23 = o23 + amount * (o23 - b23);
            f32x4 v;
            v.x = fminf(fmaxf(v01.x, 0.0f), 1.0f);
            v.y = fminf(fmaxf(v01.y, 0.0f), 1.0f);
            v.z = fminf(fmaxf(v23.x, 0.0f), 1.0f);
            v.w = fminf(fmaxf(v23.y, 0.0f), 1.0f);
            __builtin_nontemporal_store(v, (f32x4*)(dst + (size_t)ro * IMG_W + base));
        }
    }
}

extern "C" void kernel_launch(void* const* d_in, const int* in_sizes, int n_in,
                              void* d_out, int out_size, void* d_ws, size_t ws_size,
                              hipStream_t stream) {
    const float* img    = (const float*)d_in[0];
    const float* params = (const float*)d_in[1];
    float* out = (float*)d_out;

    // grid.x: 32 row-groups (4 waves x CHUNK=4 rows each) x 2 half-rows
    dim3 grid((IMG_H / (CHUNK * NWAVES)) * 2, 16 * 3);   // (64, 48)
    dim3 block(NTHREADS);
    usm_kernel<<<grid, block, 0, stream>>>(img, params, out);
}

// Round 8
// 22.064 us; speedup vs baseline: 1.1385x; 1.1074x over previous
//
#include <hip/hip_runtime.h>

#define KSIZE 5
#define HALF 2
#define IMG_W 512
#define IMG_H 512
#define HALF_W 256                 // px per wave (half a row)
#define CHUNK 4                    // output rows per wave
#define NLOADS (CHUNK + 2 * HALF)  // 8 input rows per wave
#define NTHREADS 256
#define NWAVES (NTHREADS / 64)
#define NBLOCKS (48 * 64)          // 3072 = (16*3 channels) x (32 rowgrps x 2 halves)
#define NXCD 8
#define PER_XCD (NBLOCKS / NXCD)   // 384

typedef float f32x2 __attribute__((ext_vector_type(2)));
typedef float f32x4 __attribute__((ext_vector_type(4)));

__device__ __forceinline__ int reflect_idx(int i, int n) {
    // jnp.pad mode='reflect' (edge not repeated)
    if (i < 0) i = -i;
    if (i >= n) i = 2 * n - 2 - i;
    return i;
}

__global__ __launch_bounds__(NTHREADS)
void usm_kernel(const float* __restrict__ img,
                const float* __restrict__ params,
                float* __restrict__ out) {
    // ---- XCD-aware bijective swizzle: HW sends consecutive blockIdx round-robin
    // to XCDs; remap so each XCD owns a CONTIGUOUS span of logical tiles
    // (6 full channels -> all vertical-halo sharing stays inside one XCD's L2).
    const int d = blockIdx.x;
    const int L = (d & (NXCD - 1)) * PER_XCD + (d >> 3);
    const int bc     = L >> 6;              // b*3 + c
    const int rem    = L & 63;
    const int rowgrp = rem >> 1;            // 0..31
    const int half   = rem & 1;             // 0: px 0..255, 1: px 256..511

    const int b      = bc / 3;
    const int wave   = threadIdx.x >> 6;
    const int lane   = threadIdx.x & 63;
    const int r0     = (rowgrp * NWAVES + wave) * CHUNK;
    const int c0     = half * HALF_W;
    const int base   = c0 + 4 * lane;       // first px this lane owns

    // --- per-batch gaussian taps + sharpen amount
    float sigma  = 2.0f * params[b * 2 + 0];
    sigma        = fmaxf(sigma, 0.001f);
    const float amount = 2.0f * params[b * 2 + 1];

    float k[KSIZE];
    float ksum = 0.0f;
    const float inv2s2 = 1.0f / (2.0f * sigma * sigma);
#pragma unroll
    for (int i = 0; i < KSIZE; ++i) {
        const float x = (float)(i - HALF);
        k[i] = expf(-x * x * inv2s2);
        ksum += k[i];
    }
    const float kinv = 1.0f / ksum;
#pragma unroll
    for (int i = 0; i < KSIZE; ++i) k[i] *= kinv;

    const float* src = img + (size_t)bc * IMG_H * IMG_W;
    float*       dst = out + (size_t)bc * IMG_H * IMG_W;

    // clamped bases for the two 8B halo loads (uniform per lane, computed once)
    int lb = base - 2; lb = lb < 0   ? 0   : lb;
    int rb = base + 4; rb = rb > 510 ? 510 : rb;

    f32x2 h[KSIZE][2];   // ring of h-conv rows, packed px pairs (static-indexed)
    f32x2 o[3][2];       // ring of original rows, packed      (static-indexed)

#pragma unroll
    for (int s = 0; s < NLOADS; ++s) {
        // ---- load row slice: one aligned 16B + two overlapping 8B halo loads
        const int ri = reflect_idx(r0 + s - HALF, IMG_H);
        const float* row = src + (size_t)ri * IMG_W;
        const f32x4 a = *(const f32x4*)(row + base);       // px base..base+3
        const f32x2 L2 = *(const f32x2*)(row + lb);        // px base-2,base-1 (clamped)
        const f32x2 R2 = *(const f32x2*)(row + rb);        // px base+4,base+5 (clamped)

        // window x[0..7] = px base-2 .. base+5, with reflect at image edges
        const float x0 = (base == 0)   ? a.z : L2.x;  // reflect: x[-2]=x[2]
        const float x1 = (base == 0)   ? a.y : L2.y;  // reflect: x[-1]=x[1]
        const float x6 = (base == 508) ? a.z : R2.x;  // reflect: x[512]=x[510]
        const float x7 = (base == 508) ? a.y : R2.y;  // reflect: x[513]=x[509]

        // packed pairs: P* aligned, M* misaligned
        const f32x2 P0 = {x0, x1};
        const f32x2 P1 = {a.x, a.y};
        const f32x2 P2 = {a.z, a.w};
        const f32x2 P3 = {x6, x7};
        const f32x2 M0 = {x1, a.x};
        const f32x2 M1 = {a.y, a.z};
        const f32x2 M2 = {a.w, x6};

        // ---- horizontal conv (packed): t01 = conv at px base,base+1; t23 at +2,+3
        f32x2 t01 = k[0] * P0 + k[1] * M0 + k[2] * P1 + k[3] * M1 + k[4] * P2;
        f32x2 t23 = k[0] * P1 + k[1] * M1 + k[2] * P2 + k[3] * M2 + k[4] * P3;
        h[s % KSIZE][0] = t01;
        h[s % KSIZE][1] = t23;

        // ---- original row ring (packed)
        o[s % 3][0] = P1;
        o[s % 3][1] = P2;

        // ---- once 5 h-rows live, emit output row ro = r0 + s - 4
        if (s >= 2 * HALF) {
            const int ro = r0 + s - 2 * HALF;
            const int oc = (s - HALF) % 3;

            f32x2 b01 = {0.0f, 0.0f}, b23 = {0.0f, 0.0f};
#pragma unroll
            for (int j = 0; j < KSIZE; ++j) {
                b01 += k[j] * h[(s - 2 * HALF + j) % KSIZE][0];
                b23 += k[j] * h[(s - 2 * HALF + j) % KSIZE][1];
            }
            const f32x2 o01 = o[oc][0];
            const f32x2 o23 = o[oc][1];
            f32x2 v01 = o01 + amount * (o01 - b01);
            f32x2 v23 = o23 + amount * (o23 - b23);
            f32x4 v;
            v.x = fminf(fmaxf(v01.x, 0.0f), 1.0f);
            v.y = fminf(fmaxf(v01.y, 0.0f), 1.0f);
            v.z = fminf(fmaxf(v23.x, 0.0f), 1.0f);
            v.w = fminf(fmaxf(v23.y, 0.0f), 1.0f);
            __builtin_nontemporal_store(v, (f32x4*)(dst + (size_t)ro * IMG_W + base));
        }
    }
}

extern "C" void kernel_launch(void* const* d_in, const int* in_sizes, int n_in,
                              void* d_out, int out_size, void* d_ws, size_t ws_size,
                              hipStream_t stream) {
    const float* img    = (const float*)d_in[0];
    const float* params = (const float*)d_in[1];
    float* out = (float*)d_out;

    dim3 grid(NBLOCKS);              // flattened; swizzled in-kernel
    dim3 block(NTHREADS);
    usm_kernel<<<grid, block, 0, stream>>>(img, params, out);
}